// Round 10
// baseline (13357.536 us; speedup 1.0000x reference)
//
#include <hip/hip_runtime.h>

typedef unsigned short u16;
typedef unsigned int u32;
typedef __attribute__((ext_vector_type(8))) unsigned short ushort8;
typedef __attribute__((ext_vector_type(4))) float f32x4;
typedef __attribute__((ext_vector_type(2))) float f32x2;
typedef __attribute__((ext_vector_type(4))) unsigned int u32x4;
typedef __attribute__((ext_vector_type(8))) __bf16 bf16x8;

#define N_B 256
#define LSEQ 128
#define AROW 2304   // 768 (h1) + 2*768 (h2 double-buffer phases)
#define NBLK 256

#define MFMA_B16(a, b, c) __builtin_amdgcn_mfma_f32_16x16x32_bf16( \
    __builtin_bit_cast(bf16x8, a), __builtin_bit_cast(bf16x8, b), c, 0, 0, 0)

// plain cached staging (read-only weights)
#define GLLDS(gp, lp) __builtin_amdgcn_global_load_lds( \
    (const __attribute__((address_space(1))) void*)(gp), \
    (__attribute__((address_space(3))) void*)(lp), 16, 0, 0)
// coherent staging (mutable cross-block data): aux=17 = sc0|sc1
#define GLLDS_C(gp, lp) __builtin_amdgcn_global_load_lds( \
    (const __attribute__((address_space(1))) void*)(gp), \
    (__attribute__((address_space(3))) void*)(lp), 16, 0, 17)

#define ATOMIC_LD(p) __hip_atomic_load((p), __ATOMIC_RELAXED, __HIP_MEMORY_SCOPE_AGENT)
#define ATOMIC_ST(p, v) __hip_atomic_store((p), (v), __ATOMIC_RELAXED, __HIP_MEMORY_SCOPE_AGENT)

// 16B coherent (sc0|sc1) vector store: write-through to the MALL coherence point
__device__ __forceinline__ void st16_sc(void* p, u32x4 v) {
  asm volatile("global_store_dwordx4 %0, %1, off sc0 sc1" :: "v"(p), "v"(v) : "memory");
}

// ---- workspace layout (byte offsets) ----
#define OFF_BP2   0ull
#define SZ_BP2    (48ull*192*512*2)
#define OFF_BP1   (OFF_BP2 + SZ_BP2)
#define SZ_BP1    (24ull*192*512*2)
#define OFF_W1P   (OFF_BP1 + SZ_BP1)
#define SZ_W1P    (24ull*32*512*2)
#define OFF_WIH1T (OFF_W1P + SZ_W1P)
#define SZ_WIH1T  (9ull*3072*4)
#define OFF_BS1   (OFF_WIH1T + SZ_WIH1T)
#define OFF_BS2   (OFF_BS1 + 3072*4)
#define OFF_W8Q   (OFF_BS2 + 3072*4)       // Wih1 row 8, quad-interleaved [c][q]
#define OFF_G1P   (OFF_W8Q + 3072*4)       // quad-interleaved [n][c 0..767][q 0..3] fp32
#define SZ_G1P    (256ull*3072*4)
#define OFF_ZERO  (OFF_G1P + SZ_G1P)
#define OFF_ACAT  OFF_ZERO
#define SZ_ACAT   (256ull*2304*2)
#define OFF_C1    (OFF_ACAT + SZ_ACAT)
#define OFF_C2    (OFF_C1 + 256ull*768*4)
#define OFF_SB    (OFF_C2 + 256ull*768*4)
#define OFF_BAR   (OFF_SB + 1024)          // flags: 4 clusters x 128 uints at bar+32
#define SZ_BAR    (128 + 256*32*4)
#define OFF_END   (OFF_BAR + SZ_BAR)
#define ZERO_BYTES (OFF_END - OFF_ZERO)

__device__ __forceinline__ float sigf(float v) { return 1.f / (1.f + __expf(-v)); }
__device__ __forceinline__ float tanhfast(float v) { return 1.f - 2.f / (__expf(2.f * v) + 1.f); }
__device__ __forceinline__ u16 f2bf(float f) {
  union { float f; unsigned u; } v; v.f = f;
  unsigned r = v.u + 0x7fffu + ((v.u >> 16) & 1u);   // round-to-nearest-even
  return (u16)(r >> 16);
}

struct Params {
  const float* x;
  const u16* Bp2; const u16* Bp1; const u16* W1p;
  const float* Wih1t; const float* bs1; const float* bs2; const float* w8q;
  const float* b1; const float* W2; const float* b2;
  u16* Acat; float* g1q; float* c1; float* c2; float* sb;
  unsigned* bar;
  float* outs; float* stores;
};

// ---------------------------------------------------------------------------
// Flag sync (rounds 6-9-proven protocol, dense flags). Per-cluster layout
// (cfl = bar+32+c*128): [0..47]=g2done [48..63]=g1done [96..111]=hdone.
// Monotone counters; producer drains its sc1 data stores (vmcnt 0) before
// the flag store; consumer polls with relaxed sc1 loads (no cache-wide
// maintenance anywhere). DAG/step: hdone(t-1) -> {gates2 || g1p} ->
// g2done -> H(FC+act, also needs all g1done) -> hdone(t). No fdone/pbuf.
// ---------------------------------------------------------------------------
__device__ __forceinline__ void waitflags(const unsigned* f, int n, unsigned target, int tid) {
  if (tid < 64) {
    for (;;) {
      unsigned v = (tid < n) ? ATOMIC_LD(f + tid) : target;
      if (__all((int)(v >= target))) break;
      __builtin_amdgcn_s_sleep(1);
    }
  }
  __syncthreads();
}
__device__ __forceinline__ void setflag(unsigned* f, unsigned v) {
  asm volatile("s_waitcnt vmcnt(0)" ::: "memory");
  __syncthreads();
  if (threadIdx.x == 0) ATOMIC_ST(f, v);
}

// ---------------------------------------------------------------------------
// One-time packing (round-1 verified layouts + w8q).
// ---------------------------------------------------------------------------
__global__ void pack_kernel(const float* __restrict__ Wih1, const float* __restrict__ bih1,
                            const float* __restrict__ Whh1, const float* __restrict__ bhh1,
                            const float* __restrict__ Wih2, const float* __restrict__ bih2,
                            const float* __restrict__ Whh2, const float* __restrict__ bhh2,
                            const float* __restrict__ W1,
                            u16* __restrict__ Bp2, u16* __restrict__ Bp1, u16* __restrict__ W1p,
                            float* __restrict__ Wih1t, float* __restrict__ bs1,
                            float* __restrict__ bs2, float* __restrict__ w8q) {
  const long NB2 = 48l * 192 * 512, NB1 = 24l * 192 * 512, NW1 = 24l * 32 * 512, NT = 9l * 3072;
  const long total = NB2 + NB1 + NW1 + NT + 3072 * 3;
  for (long idx = (long)blockIdx.x * 256 + threadIdx.x; idx < total; idx += (long)gridDim.x * 256) {
    if (idx < NB2) {                       // Wcat2 = [W_ih2 ; W_hh2] (K=1536)
      long kt = idx / (192 * 512); long r = idx % (192 * 512);
      int jt = (int)(r / 512); int s = (int)(r % 512);
      int ll = s >> 3, e = s & 7;
      int k = (int)kt * 32 + ((ll >> 4) * 8) + e;
      int j = jt * 16 + (ll & 15);
      float v = (k < 768) ? Wih2[j * 768 + k] : Whh2[j * 768 + k - 768];
      Bp2[idx] = f2bf(v);
    } else if (idx < NB2 + NB1) {          // W_hh1 (K=768)
      long i = idx - NB2;
      long kt = i / (192 * 512); long r = i % (192 * 512);
      int jt = (int)(r / 512); int s = (int)(r % 512);
      int ll = s >> 3, e = s & 7;
      int k = (int)kt * 32 + ((ll >> 4) * 8) + e;
      int j = jt * 16 + (ll & 15);
      Bp1[i] = f2bf(Whh1[j * 768 + k]);
    } else if (idx < NB2 + NB1 + NW1) {    // W1 (K=768, N=512)
      long i = idx - NB2 - NB1;
      long kt = i / (32 * 512); long r = i % (32 * 512);
      int jt = (int)(r / 512); int s = (int)(r % 512);
      int ll = s >> 3, e = s & 7;
      int k = (int)kt * 32 + ((ll >> 4) * 8) + e;
      int j = jt * 16 + (ll & 15);
      W1p[i] = f2bf(W1[j * 768 + k]);
    } else if (idx < NB2 + NB1 + NW1 + NT) {  // W_ih1 transposed (fp32)
      long i = idx - NB2 - NB1 - NW1;
      int k = (int)(i / 3072), j = (int)(i % 3072);
      Wih1t[i] = Wih1[j * 9 + k];
    } else {
      long i = idx - NB2 - NB1 - NW1 - NT;
      if (i < 3072) bs1[i] = bih1[i] + bhh1[i];
      else if (i < 6144) { long j = i - 3072; bs2[j] = bih2[j] + bhh2[j]; }
      else {                               // w8q[c*4+q] = Wih1[(q*768+c)*9 + 8]
        long cq = i - 6144; int cc = (int)(cq >> 2), q = (int)(cq & 3);
        w8q[cq] = Wih1[(q * 768 + cc) * 9 + 8];
      }
    }
  }
}

// ---------------------------------------------------------------------------
// Persistent kernel: 4 independent 64-row clusters x 64 blocks.
//   local 0..47 : gates2 GEMM (h2-half early-start) + h2/c2 update.
//   local 48..63: g1p GEMM (wave=quadrant, 16B g1q stores) + fused FC + H.
// ---------------------------------------------------------------------------
__global__ __launch_bounds__(256) void lstm_fused(Params P) {
  __shared__ ushort8 sbuf[48 * 64];     // 48 KB staging / g1p transpose / g1q mirror
  __shared__ float xsb[64][8];          // 2 KB x rows
  __shared__ u16 h2s[4][768];           // 6 KB h2 rows for fused FC
  __shared__ float red[4][4];
  __shared__ float csh[8];
  float (*fbuf)[64][16] = (float(*)[64][16])sbuf;  // 16 KB overlay, post-K-loop only
  const int tid = threadIdx.x, l = tid & 63, w = tid >> 6;
  const int bid = blockIdx.x;
  const int c = bid >> 6, local = bid & 63;
  const int rowbase = c * 64;
  unsigned* cfl = P.bar + 32 + c * 128;

  if (local < 48) {
    // ================= gates2 blocks =================
    const int mg = local;
    setflag(cfl + local, 1u);                        // bootstrap: h2(-1)=0 published
    for (int t = 0; t < 128; ++t) {
      const int rdbase = 768 + (t & 1) * 768;        // h2(t-1)
      const int wrbase = 768 + ((t + 1) & 1) * 768;  // h2(t)
      auto stage_g2 = [&](int kc, int slot) {
#pragma unroll
        for (int i = 0; i < 4; ++i) {
          int f = w * 4 + i;
          if (f < 8) {                               // A (mutable): coherent
            int kt2 = f >> 2, rt = f & 3, kt = kc * 2 + kt2;
            int col = (kt >= 24) ? (rdbase + (kt - 24) * 32 + ((l >> 4) * 8))
                                 : (kt * 32 + ((l >> 4) * 8));
            const u16* gp = P.Acat + (rowbase + rt * 16 + (l & 15)) * AROW + col;
            GLLDS_C(gp, &sbuf[(slot * 16 + f) * 64]);
          } else {                                   // B (weights): plain cached
            int g = f - 8, kt2 = g >> 2, q = g & 3, kt = kc * 2 + kt2;
            const u16* gp = P.Bp2 + (((long)(kt * 192 + q * 48 + mg)) << 9) + l * 8;
            GLLDS(gp, &sbuf[(slot * 16 + f) * 64]);
          }
        }
      };
      auto kc_of = [](int g) { int k = g + 12; return (k >= 24) ? k - 24 : k; };
      // h2-half (kc 12..23) needs only g2done(t-1); h1-half waits hdone mid-loop
      waitflags(cfl, 48, (unsigned)(t + 1), tid);
      f32x4 acc[4] = {};
      stage_g2(kc_of(0), 0);
      stage_g2(kc_of(1), 1);
      for (int g = 0; g < 24; ++g) {
        if (g < 22) {
          if (g == 10) waitflags(cfl + 96, 16, (unsigned)(t + 1), tid);  // h1(t) ready
          stage_g2(kc_of(g + 2), (g + 2) % 3);
          asm volatile("s_waitcnt vmcnt(8)" ::: "memory");
        } else if (g == 22) {
          asm volatile("s_waitcnt vmcnt(4)" ::: "memory");
        } else {
          asm volatile("s_waitcnt vmcnt(0)" ::: "memory");
        }
        __builtin_amdgcn_s_barrier();
        __builtin_amdgcn_sched_barrier(0);
        const int base = (g % 3) * 16;
#pragma unroll
        for (int kt2 = 0; kt2 < 2; ++kt2) {
          ushort8 bfr = sbuf[(base + 8 + kt2 * 4 + w) * 64 + l];
#pragma unroll
          for (int rt = 0; rt < 4; ++rt) {
            ushort8 a = sbuf[(base + kt2 * 4 + rt) * 64 + l];
            acc[rt] = MFMA_B16(a, bfr, acc[rt]);
          }
        }
        __builtin_amdgcn_sched_barrier(0);
        __builtin_amdgcn_s_barrier();
      }
      // epilogue: quadrant exchange -> h2/c2; 16B sc1 h2 stores
#pragma unroll
      for (int rt = 0; rt < 4; ++rt)
#pragma unroll
        for (int reg = 0; reg < 4; ++reg) {
          int rl = rt * 16 + (l >> 4) * 4 + reg;
          fbuf[w][rl][l & 15] = acc[rt][reg] + P.bs2[w * 768 + mg * 16 + (l & 15)];
        }
      __syncthreads();
      for (int p = tid; p < 128; p += 256) {         // 64 rows x 2 col-octets
        int r = p >> 1, half = p & 1;
        int n = rowbase + r, mG = mg * 16 + half * 8;
        f32x4 cold0 = *(const f32x4*)(P.c2 + n * 768 + mG);
        f32x4 cold1 = *(const f32x4*)(P.c2 + n * 768 + mG + 4);
        u32 hp[4];
        f32x4 cnew0, cnew1;
#pragma unroll
        for (int k = 0; k < 8; ++k) {
          int pp = half * 8 + k;
          float gi = fbuf[0][r][pp], gf = fbuf[1][r][pp], gg = fbuf[2][r][pp], go = fbuf[3][r][pp];
          float co = (k < 4) ? cold0[k] : cold1[k - 4];
          float cn = sigf(gf) * co + sigf(gi) * tanhfast(gg);
          float h = sigf(go) * tanhfast(cn);
          if (k < 4) cnew0[k] = cn; else cnew1[k - 4] = cn;
          if (k & 1) hp[k >> 1] |= ((u32)f2bf(h)) << 16; else hp[k >> 1] = f2bf(h);
        }
        *(f32x4*)(P.c2 + n * 768 + mG) = cnew0;
        *(f32x4*)(P.c2 + n * 768 + mG + 4) = cnew1;
        st16_sc(P.Acat + n * AROW + wrbase + mG, *(u32x4*)hp);
      }
      setflag(cfl + local, (unsigned)(t + 2));       // g2done
    }
  } else {
    // ================= g1p + fused-FC + H blocks =================
    const int jb = local - 48;
    const int n0 = rowbase + jb * 4;
    for (int t = -1; t < 128; ++t) {
      if (t < 127) {
        // ---- g1p(t): 64 rows; wave w = gate quadrant w, cols [jb*48,(jb+1)*48) ----
        if (t >= 0) waitflags(cfl + 96, 16, (unsigned)(t + 1), tid);   // h1(t) ready
        for (int p = tid; p < 512; p += 256)
          xsb[p >> 3][p & 7] = P.x[((rowbase + (p >> 3)) * LSEQ + t + 1) * 8 + (p & 7)];
        __syncthreads();
        f32x4 acc[3][4] = {};
        if (t >= 0) {
          auto stage_g1 = [&](int kt, int slot) {
#pragma unroll
            for (int i = 0; i < 4; ++i) {
              int f = w * 4 + i;
              if (f < 4) {                           // A (mutable h1): coherent
                const u16* gp = P.Acat + (rowbase + f * 16 + (l & 15)) * AROW + kt * 32 + ((l >> 4) * 8);
                GLLDS_C(gp, &sbuf[(slot * 16 + f) * 64]);
              } else {                               // B: tile (q, jj) -> jt = q*48+jb*3+jj
                int jt_l = f - 4;
                int q = jt_l / 3, jj = jt_l - q * 3;
                const u16* gp = P.Bp1 + (((long)(kt * 192 + q * 48 + jb * 3 + jj)) << 9) + l * 8;
                GLLDS(gp, &sbuf[(slot * 16 + f) * 64]);
              }
            }
          };
          stage_g1(0, 0);
          stage_g1(1, 1);
          for (int kt = 0; kt < 24; ++kt) {
            if (kt < 22) {
              stage_g1(kt + 2, (kt + 2) % 3);
              asm volatile("s_waitcnt vmcnt(8)" ::: "memory");
            } else if (kt == 22) {
              asm volatile("s_waitcnt vmcnt(4)" ::: "memory");
            } else {
              asm volatile("s_waitcnt vmcnt(0)" ::: "memory");
            }
            __builtin_amdgcn_s_barrier();
            __builtin_amdgcn_sched_barrier(0);
            const int base = (kt % 3) * 16;
            ushort8 a_[4];
#pragma unroll
            for (int rt = 0; rt < 4; ++rt) a_[rt] = sbuf[(base + rt) * 64 + l];
#pragma unroll
            for (int jj = 0; jj < 3; ++jj) {
              ushort8 bfr = sbuf[(base + 4 + w * 3 + jj) * 64 + l];
#pragma unroll
              for (int rt = 0; rt < 4; ++rt)
                acc[jj][rt] = MFMA_B16(a_[rt], bfr, acc[jj][rt]);
            }
            __builtin_amdgcn_sched_barrier(0);
            __builtin_amdgcn_s_barrier();
          }
        }
        // epilogue: v = acc + bs1 + x(t+1) dot Wih1[:,0:8]; LDS transpose -> 16B stores
        float wc[3][8], bsv[3];
#pragma unroll
        for (int jj = 0; jj < 3; ++jj) {
          int j = w * 768 + (jb * 3 + jj) * 16 + (l & 15);
          bsv[jj] = P.bs1[j];
#pragma unroll
          for (int k = 0; k < 8; ++k) wc[jj][k] = P.Wih1t[k * 3072 + j];
        }
        float* eps = (float*)sbuf;                   // [row64][cin48][quad4]
#pragma unroll
        for (int rt = 0; rt < 4; ++rt)
#pragma unroll
          for (int reg = 0; reg < 4; ++reg) {
            int rl = rt * 16 + (l >> 4) * 4 + reg;
            float xv[8];
#pragma unroll
            for (int k = 0; k < 8; ++k) xv[k] = xsb[rl][k];
#pragma unroll
            for (int jj = 0; jj < 3; ++jj) {
              float v = acc[jj][rt][reg] + bsv[jj];
#pragma unroll
              for (int k = 0; k < 8; ++k) v += xv[k] * wc[jj][k];
              eps[rl * 192 + (jj * 16 + (l & 15)) * 4 + w] = v;
            }
          }
        __syncthreads();
#pragma unroll
        for (int k2 = 0; k2 < 12; ++k2) {
          int idx = tid + k2 * 256;                  // 0..3071
          int row = idx / 48, cl = idx - row * 48;
          u32x4 v = *(const u32x4*)(eps + row * 192 + cl * 4);
          st16_sc(P.g1q + (rowbase + row) * 3072 + (jb * 48 + cl) * 4, v);
        }
        setflag(cfl + 48 + jb, (unsigned)(t + 2));   // g1done

        // stage 48KB g1q mirror for own 4 rows (overlaps g2done wait below)
        waitflags(cfl + 48, 16, (unsigned)(t + 2), tid);
#pragma unroll
        for (int i = 0; i < 12; ++i) {
          int f = w * 12 + i;
          const float* gp = P.g1q + n0 * 3072 + f * 256 + l * 4;
          GLLDS_C(gp, (char*)sbuf + f * 1024);
        }
      }

      // ---- fused FC: out(t) for own 4 rows (t>=0) ----
      if (t >= 0) {
        waitflags(cfl, 48, (unsigned)(t + 2), tid);  // all g2done: h2(t) ready
        const int h2rd = 768 + ((t + 1) & 1) * 768;
        for (int i = w; i < 6; i += 4) {             // stage 4x1536B h2 rows
          int bo = i * 1024 + l * 16;
          int row = bo / 1536, cb = bo - row * 1536;
          const u16* gp = P.Acat + (n0 + row) * AROW + h2rd + cb / 2;
          GLLDS_C(gp, (char*)h2s + i * 1024);
        }
        asm volatile("s_waitcnt vmcnt(0)" ::: "memory");
        __syncthreads();
        f32x4 fa[8] = {};
        const u16* bb = P.W1p + l * 8;
        for (int kt = 0; kt < 24; ++kt) {
          ushort8 a = *(const ushort8*)((const char*)h2s + (l & 3) * 1536 + kt * 64 + ((l >> 4) * 8) * 2);
#pragma unroll
          for (int i = 0; i < 8; ++i) {
            ushort8 b = *(const ushort8*)(bb + (((long)kt * 32 + (w * 8 + i)) << 9));
            fa[i] = MFMA_B16(a, b, fa[i]);
          }
        }
        float pr[4] = {0.f, 0.f, 0.f, 0.f};
#pragma unroll
        for (int i = 0; i < 8; ++i) {
          int col = (w * 8 + i) * 16 + (l & 15);
          float b1v = P.b1[col], w2v = P.W2[col];
#pragma unroll
          for (int reg = 0; reg < 4; ++reg)
            pr[reg] += fmaxf(fa[i][reg] + b1v, 0.f) * w2v;
        }
#pragma unroll
        for (int mm = 1; mm < 16; mm <<= 1)
#pragma unroll
          for (int reg = 0; reg < 4; ++reg) pr[reg] += __shfl_xor(pr[reg], mm);
        if (l == 0)
#pragma unroll
          for (int reg = 0; reg < 4; ++reg) red[w][reg] = pr[reg];
        __syncthreads();
      }

      // ---- H: out/cs/act ----
      if (tid < 4) {
        int n = n0 + tid;
        float ov = 0.f;
        if (t >= 0) {
          ov = red[0][tid] + red[1][tid] + red[2][tid] + red[3][tid] + P.b2[0];
          P.outs[n * LSEQ + t] = ov;
        }
        if (t < 127) {
          float cs = P.sb[n] + P.x[(n * LSEQ + t + 1) * 8] - ov;   // exact fp32
          P.sb[n] = cs;
          P.stores[n * LSEQ + t + 1] = cs;
          csh[tid] = cs;
        }
      }
      if (t < 127) {
        asm volatile("s_waitcnt vmcnt(0)" ::: "memory");   // g1q mirror complete
        __syncthreads();
        const int r = tid >> 6, l2 = tid & 63;
        const int n = n0 + r;
        const float* ldsrow = (const float*)sbuf + r * 3072;  // [cin768][quad4]
        float cs = csh[r];
        for (int idx = l2; idx < 96; idx += 64) {    // 8 cols per idx
          int m = idx * 8;
          u32 hp[4];
          f32x4 c1v0 = *(const f32x4*)(P.c1 + n * 768 + m);
          f32x4 c1v1 = *(const f32x4*)(P.c1 + n * 768 + m + 4);
          f32x4 nc0, nc1;
#pragma unroll
          for (int k = 0; k < 8; ++k) {
            int mm = m + k;
            f32x4 q = *(const f32x4*)(ldsrow + mm * 4);
            f32x4 wq = *(const f32x4*)(P.w8q + mm * 4);
            float g0 = q[0] + cs * wq[0], g1v = q[1] + cs * wq[1];
            float g2v = q[2] + cs * wq[2], g3v = q[3] + cs * wq[3];
            float co = (k < 4) ? c1v0[k] : c1v1[k - 4];
            float cn = sigf(g1v) * co + sigf(g0) * tanhfast(g2v);
            float h = sigf(g3v) * tanhfast(cn);
            if (k < 4) nc0[k] = cn; else nc1[k - 4] = cn;
            if (k & 1) hp[k >> 1] |= ((u32)f2bf(h)) << 16; else hp[k >> 1] = f2bf(h);
          }
          *(f32x4*)(P.c1 + n * 768 + m) = nc0;
          *(f32x4*)(P.c1 + n * 768 + m + 4) = nc1;
          st16_sc(P.Acat + n * AROW + m, *(u32x4*)hp);
        }
        setflag(cfl + 96 + jb, (unsigned)(t + 2));   // hdone
      }
    }
  }
}

extern "C" void kernel_launch(void* const* d_in, const int* in_sizes, int n_in,
                              void* d_out, int out_size, void* d_ws, size_t ws_size,
                              hipStream_t stream) {
  const float* x    = (const float*)d_in[0];
  const float* Wih1 = (const float*)d_in[1];
  const float* bih1 = (const float*)d_in[2];
  const float* Whh1 = (const float*)d_in[3];
  const float* bhh1 = (const float*)d_in[4];
  const float* Wih2 = (const float*)d_in[5];
  const float* bih2 = (const float*)d_in[6];
  const float* Whh2 = (const float*)d_in[7];
  const float* bhh2 = (const float*)d_in[8];
  const float* W1   = (const float*)d_in[9];
  const float* b1   = (const float*)d_in[10];
  const float* W2   = (const float*)d_in[11];
  const float* b2   = (const float*)d_in[12];

  char* ws = (char*)d_ws;
  u16* Bp2 = (u16*)(ws + OFF_BP2);
  u16* Bp1 = (u16*)(ws + OFF_BP1);
  u16* W1p = (u16*)(ws + OFF_W1P);
  float* Wih1t = (float*)(ws + OFF_WIH1T);
  float* bs1 = (float*)(ws + OFF_BS1);
  float* bs2 = (float*)(ws + OFF_BS2);
  float* w8q = (float*)(ws + OFF_W8Q);
  float* g1q = (float*)(ws + OFF_G1P);
  u16* Acat = (u16*)(ws + OFF_ACAT);
  float* c1 = (float*)(ws + OFF_C1);
  float* c2 = (float*)(ws + OFF_C2);
  float* sb = (float*)(ws + OFF_SB);
  unsigned* bar = (unsigned*)(ws + OFF_BAR);
  float* outs = (float*)d_out;
  float* stores = outs + N_B * LSEQ;

  pack_kernel<<<2048, 256, 0, stream>>>(Wih1, bih1, Whh1, bhh1, Wih2, bih2, Whh2, bhh2, W1,
                                        Bp2, Bp1, W1p, Wih1t, bs1, bs2, w8q);
  (void)hipMemsetAsync(ws + OFF_ZERO, 0, ZERO_BYTES, stream);

  Params Pr = {x, Bp2, Bp1, W1p, Wih1t, bs1, bs2, w8q, b1, W2, b2,
               Acat, g1q, c1, c2, sb, bar, outs, stores};
  lstm_fused<<<NBLK, 256, 0, stream>>>(Pr);
}

// Round 11
// 3159.232 us; speedup vs baseline: 4.2281x; 4.2281x over previous
//
#include <hip/hip_runtime.h>

typedef unsigned short u16;
typedef unsigned int u32;
typedef __attribute__((ext_vector_type(8))) unsigned short ushort8;
typedef __attribute__((ext_vector_type(4))) float f32x4;
typedef __attribute__((ext_vector_type(2))) float f32x2;
typedef __attribute__((ext_vector_type(4))) unsigned int u32x4;
typedef __attribute__((ext_vector_type(8))) __bf16 bf16x8;

#define N_B 256
#define LSEQ 128
#define AROW 2304   // 768 (h1) + 2*768 (h2 double-buffer phases)
#define NBLK 256

#define MFMA_B16(a, b, c) __builtin_amdgcn_mfma_f32_16x16x32_bf16( \
    __builtin_bit_cast(bf16x8, a), __builtin_bit_cast(bf16x8, b), c, 0, 0, 0)

// plain cached staging (read-only weights)
#define GLLDS(gp, lp) __builtin_amdgcn_global_load_lds( \
    (const __attribute__((address_space(1))) void*)(gp), \
    (__attribute__((address_space(3))) void*)(lp), 16, 0, 0)
// coherent staging (mutable cross-block data): aux=17 = sc0|sc1
#define GLLDS_C(gp, lp) __builtin_amdgcn_global_load_lds( \
    (const __attribute__((address_space(1))) void*)(gp), \
    (__attribute__((address_space(3))) void*)(lp), 16, 0, 17)

#define ATOMIC_LD(p) __hip_atomic_load((p), __ATOMIC_RELAXED, __HIP_MEMORY_SCOPE_AGENT)
#define ATOMIC_ST(p, v) __hip_atomic_store((p), (v), __ATOMIC_RELAXED, __HIP_MEMORY_SCOPE_AGENT)

// 16B coherent (sc0|sc1) vector store: write-through to the MALL coherence point
__device__ __forceinline__ void st16_sc(void* p, u32x4 v) {
  asm volatile("global_store_dwordx4 %0, %1, off sc0 sc1" :: "v"(p), "v"(v) : "memory");
}
// direct global->register 16B load (weights, plain cached); counted in OUR vmcnt FIFO
#define LOADB(dst, gp) asm volatile("global_load_dwordx4 %0, %1, off" : "=v"(dst) : "v"(gp))
#define VMW(N) asm volatile("s_waitcnt vmcnt(" #N ")" ::: "memory")

// ---- workspace layout (byte offsets) ----
#define OFF_BP2   0ull
#define SZ_BP2    (48ull*192*512*2)
#define OFF_BP1   (OFF_BP2 + SZ_BP2)
#define SZ_BP1    (24ull*192*512*2)
#define OFF_W1P   (OFF_BP1 + SZ_BP1)
#define SZ_W1P    (24ull*32*512*2)
#define OFF_WIH1T (OFF_W1P + SZ_W1P)
#define SZ_WIH1T  (9ull*3072*4)
#define OFF_BS1   (OFF_WIH1T + SZ_WIH1T)
#define OFF_BS2   (OFF_BS1 + 3072*4)
#define OFF_W8Q   (OFF_BS2 + 3072*4)       // Wih1 row 8, quad-interleaved [c][q]
#define OFF_G1P   (OFF_W8Q + 3072*4)       // quad-interleaved [n][c 0..767][q 0..3] fp32
#define SZ_G1P    (256ull*3072*4)
#define OFF_PBUF  (OFF_G1P + SZ_G1P)
#define SZ_PBUF   (256ull*8*4)
#define OFF_ZERO  (OFF_PBUF + SZ_PBUF)
#define OFF_ACAT  OFF_ZERO
#define SZ_ACAT   (256ull*2304*2)
#define OFF_C1    (OFF_ACAT + SZ_ACAT)
#define OFF_C2    (OFF_C1 + 256ull*768*4)
#define OFF_SB    (OFF_C2 + 256ull*768*4)
#define OFF_BAR   (OFF_SB + 1024)          // flags: 4 clusters x 128 uints at bar+32
#define SZ_BAR    (128 + 256*32*4)
#define OFF_END   (OFF_BAR + SZ_BAR)
#define ZERO_BYTES (OFF_END - OFF_ZERO)

__device__ __forceinline__ float sigf(float v) { return 1.f / (1.f + __expf(-v)); }
__device__ __forceinline__ float tanhfast(float v) { return 1.f - 2.f / (__expf(2.f * v) + 1.f); }
__device__ __forceinline__ u16 f2bf(float f) {
  union { float f; unsigned u; } v; v.f = f;
  unsigned r = v.u + 0x7fffu + ((v.u >> 16) & 1u);   // round-to-nearest-even
  return (u16)(r >> 16);
}

struct Params {
  const float* x;
  const u16* Bp2; const u16* Bp1; const u16* W1p;
  const float* Wih1t; const float* bs1; const float* bs2; const float* w8q;
  const float* b1; const float* W2; const float* b2;
  u16* Acat; float* g1q; float* c1; float* c2; float* sb; float* pbuf;
  unsigned* bar;
  float* outs; float* stores;
};

// ---------------------------------------------------------------------------
// Flag sync (rounds 6-9-proven): producer drains its sc1 data stores
// (vmcnt 0) + syncthreads -> relaxed sc1 flag store; consumer wave-0 polls
// relaxed sc1, then syncthreads. No cache-wide maintenance anywhere.
// Per-cluster layout (cfl = bar+32+c*128): [0..47]=g2done [48..63]=g1done
// [64..95]=fdone [96..111]=hdone. Monotone counters.
// ---------------------------------------------------------------------------
__device__ __forceinline__ void waitflags(const unsigned* f, int n, unsigned target, int tid) {
  if (tid < 64) {
    for (;;) {
      unsigned v = (tid < n) ? ATOMIC_LD(f + tid) : target;
      if (__all((int)(v >= target))) break;
      __builtin_amdgcn_s_sleep(1);
    }
  }
  __syncthreads();
}
__device__ __forceinline__ void setflag(unsigned* f, unsigned v) {
  asm volatile("s_waitcnt vmcnt(0)" ::: "memory");
  __syncthreads();
  if (threadIdx.x == 0) ATOMIC_ST(f, v);
}

// ---------------------------------------------------------------------------
// One-time packing (round-1 verified layouts + w8q).
// ---------------------------------------------------------------------------
__global__ void pack_kernel(const float* __restrict__ Wih1, const float* __restrict__ bih1,
                            const float* __restrict__ Whh1, const float* __restrict__ bhh1,
                            const float* __restrict__ Wih2, const float* __restrict__ bih2,
                            const float* __restrict__ Whh2, const float* __restrict__ bhh2,
                            const float* __restrict__ W1,
                            u16* __restrict__ Bp2, u16* __restrict__ Bp1, u16* __restrict__ W1p,
                            float* __restrict__ Wih1t, float* __restrict__ bs1,
                            float* __restrict__ bs2, float* __restrict__ w8q) {
  const long NB2 = 48l * 192 * 512, NB1 = 24l * 192 * 512, NW1 = 24l * 32 * 512, NT = 9l * 3072;
  const long total = NB2 + NB1 + NW1 + NT + 3072 * 3;
  for (long idx = (long)blockIdx.x * 256 + threadIdx.x; idx < total; idx += (long)gridDim.x * 256) {
    if (idx < NB2) {                       // Wcat2 = [W_ih2 ; W_hh2] (K=1536)
      long kt = idx / (192 * 512); long r = idx % (192 * 512);
      int jt = (int)(r / 512); int s = (int)(r % 512);
      int ll = s >> 3, e = s & 7;
      int k = (int)kt * 32 + ((ll >> 4) * 8) + e;
      int j = jt * 16 + (ll & 15);
      float v = (k < 768) ? Wih2[j * 768 + k] : Whh2[j * 768 + k - 768];
      Bp2[idx] = f2bf(v);
    } else if (idx < NB2 + NB1) {          // W_hh1 (K=768)
      long i = idx - NB2;
      long kt = i / (192 * 512); long r = i % (192 * 512);
      int jt = (int)(r / 512); int s = (int)(r % 512);
      int ll = s >> 3, e = s & 7;
      int k = (int)kt * 32 + ((ll >> 4) * 8) + e;
      int j = jt * 16 + (ll & 15);
      Bp1[i] = f2bf(Whh1[j * 768 + k]);
    } else if (idx < NB2 + NB1 + NW1) {    // W1 (K=768, N=512)
      long i = idx - NB2 - NB1;
      long kt = i / (32 * 512); long r = i % (32 * 512);
      int jt = (int)(r / 512); int s = (int)(r % 512);
      int ll = s >> 3, e = s & 7;
      int k = (int)kt * 32 + ((ll >> 4) * 8) + e;
      int j = jt * 16 + (ll & 15);
      W1p[i] = f2bf(W1[j * 768 + k]);
    } else if (idx < NB2 + NB1 + NW1 + NT) {  // W_ih1 transposed (fp32)
      long i = idx - NB2 - NB1 - NW1;
      int k = (int)(i / 3072), j = (int)(i % 3072);
      Wih1t[i] = Wih1[j * 9 + k];
    } else {
      long i = idx - NB2 - NB1 - NW1 - NT;
      if (i < 3072) bs1[i] = bih1[i] + bhh1[i];
      else if (i < 6144) { long j = i - 3072; bs2[j] = bih2[j] + bhh2[j]; }
      else {                               // w8q[c*4+q] = Wih1[(q*768+c)*9 + 8]
        long cq = i - 6144; int cc = (int)(cq >> 2), q = (int)(cq & 3);
        w8q[cq] = Wih1[(q * 768 + cc) * 9 + 8];
      }
    }
  }
}

// ---------------------------------------------------------------------------
// Persistent kernel: 4 independent 64-row clusters x 64 blocks.
//   local 0..47 : gates2 GEMM (h2-half first; reg-B + depth-3 LDS-A) + h2/c2;
//                 local 0..31 also F (FC partials -> pbuf).
//   local 48..63: g1p GEMM (same staging scheme; wave=quadrant; 16B g1q
//                 stores via LDS transpose) + H (out/cs/h1-act).
// K-loop staging: A (mutable, sc1) via GLLDS_C into 6/8 LDS slots, depth-3
// prefetch; B (weights, cached) via asm global_load_dwordx4 into a
// compile-time-indexed register ring. One barrier per iteration (slot
// distance >= 2 guarantees no write/read overlap); exact counted vmcnt.
// ---------------------------------------------------------------------------
__global__ __launch_bounds__(256) void lstm_fused(Params P) {
  __shared__ ushort8 sbuf[48 * 64];     // 48 KB: A slots / eps transpose / g1q mirror / F stage
  __shared__ float xsb[64][8];          // 2 KB x rows
  __shared__ float csh[8];
  float (*fbuf)[64][16] = (float(*)[64][16])sbuf;  // 16 KB overlay, post-K-loop only
  const int tid = threadIdx.x, l = tid & 63, w = tid >> 6;
  const int bid = blockIdx.x;
  const int c = bid >> 6, local = bid & 63;
  const int rowbase = c * 64;
  unsigned* cfl = P.bar + 32 + c * 128;

  if (local < 48) {
    // ================= gates2 (+F) blocks =================
    const int mg = local;
    setflag(cfl + local, 1u);                        // bootstrap: h2(-1)=0 published
    for (int t = 0; t < 128; ++t) {
      const int rdbase = 768 + (t & 1) * 768;        // h2(t-1)
      const int wrbase = 768 + ((t + 1) & 1) * 768;  // h2(t)
      waitflags(cfl, 48, (unsigned)(t + 1), tid);    // peers' h2(t-1) complete

      f32x4 acc[4] = {};
      ushort8 bring[4][2];
      // tile order g: 0..11 -> h2-half (kc 12..23), 12..23 -> h1-half (kc 0..11)
      auto issueA2 = [&](int gi) {
        const int slot = gi % 6;
#pragma unroll
        for (int kt2 = 0; kt2 < 2; ++kt2) {
          int kt = ((gi < 12) ? gi + 12 : gi - 12) * 2 + kt2;
          int col = (kt >= 24) ? (rdbase + (kt - 24) * 32 + ((l >> 4) * 8))
                               : (kt * 32 + ((l >> 4) * 8));
          const u16* gp = P.Acat + (rowbase + w * 16 + (l & 15)) * AROW + col;
          GLLDS_C(gp, &sbuf[slot * 512 + (kt2 * 4 + w) * 64]);
        }
      };
      auto baddr2 = [&](int gi, int kt2) -> const u16* {
        int kt = ((gi < 12) ? gi + 12 : gi - 12) * 2 + kt2;
        return P.Bp2 + (((long)(kt * 192 + w * 48 + mg)) << 9) + l * 8;
      };
      auto g2_step = [&](int g, const ushort8 (&bu)[2]) {
        __builtin_amdgcn_s_barrier();
        __builtin_amdgcn_sched_barrier(0);
        const int sb8 = (g % 6) * 512;
#pragma unroll
        for (int kt2 = 0; kt2 < 2; ++kt2)
#pragma unroll
          for (int rt = 0; rt < 4; ++rt) {
            ushort8 a = sbuf[sb8 + (kt2 * 4 + rt) * 64 + l];
            acc[rt] = MFMA_B16(a, bu[kt2], acc[rt]);
          }
        __builtin_amdgcn_sched_barrier(0);
      };
#pragma unroll
      for (int p = 0; p < 3; ++p) {                  // prologue: tiles 0..2
        issueA2(p);
        LOADB(bring[p][0], baddr2(p, 0));
        LOADB(bring[p][1], baddr2(p, 1));
      }
      for (int ko = 0; ko < 5; ++ko) {
#pragma unroll
        for (int u = 0; u < 4; ++u) {
          const int g = ko * 4 + u;
          if (g == 9) waitflags(cfl + 96, 16, (unsigned)(t + 1), tid);  // h1(t) before tile 12 issue
          issueA2(g + 3);
          LOADB(bring[(u + 3) & 3][0], baddr2(g + 3, 0));
          LOADB(bring[(u + 3) & 3][1], baddr2(g + 3, 1));
          VMW(12);
          g2_step(g, bring[u]);
        }
      }
      issueA2(23);
      LOADB(bring[3][0], baddr2(23, 0));
      LOADB(bring[3][1], baddr2(23, 1));
      VMW(12); g2_step(20, bring[0]);
      VMW(8);  g2_step(21, bring[1]);
      VMW(4);  g2_step(22, bring[2]);
      VMW(0);  g2_step(23, bring[3]);
      __syncthreads();

      // epilogue: quadrant exchange -> h2/c2; 16B sc1 h2 stores
#pragma unroll
      for (int rt = 0; rt < 4; ++rt)
#pragma unroll
        for (int reg = 0; reg < 4; ++reg) {
          int rl = rt * 16 + (l >> 4) * 4 + reg;
          fbuf[w][rl][l & 15] = acc[rt][reg] + P.bs2[w * 768 + mg * 16 + (l & 15)];
        }
      __syncthreads();
      for (int p = tid; p < 128; p += 256) {         // 64 rows x 2 col-octets
        int r = p >> 1, half = p & 1;
        int n = rowbase + r, mG = mg * 16 + half * 8;
        f32x4 cold0 = *(const f32x4*)(P.c2 + n * 768 + mG);
        f32x4 cold1 = *(const f32x4*)(P.c2 + n * 768 + mG + 4);
        u32 hp[4];
        f32x4 cnew0, cnew1;
#pragma unroll
        for (int k = 0; k < 8; ++k) {
          int pp = half * 8 + k;
          float gi = fbuf[0][r][pp], gf = fbuf[1][r][pp], gg = fbuf[2][r][pp], go = fbuf[3][r][pp];
          float co = (k < 4) ? cold0[k] : cold1[k - 4];
          float cn = sigf(gf) * co + sigf(gi) * tanhfast(gg);
          float h = sigf(go) * tanhfast(cn);
          if (k < 4) cnew0[k] = cn; else cnew1[k - 4] = cn;
          if (k & 1) hp[k >> 1] |= ((u32)f2bf(h)) << 16; else hp[k >> 1] = f2bf(h);
        }
        *(f32x4*)(P.c2 + n * 768 + mG) = cnew0;
        *(f32x4*)(P.c2 + n * 768 + mG + 4) = cnew1;
        st16_sc(P.Acat + n * AROW + wrbase + mG, *(u32x4*)hp);
      }
      setflag(cfl + local, (unsigned)(t + 2));       // g2done

      if (local < 32) {
        // ---- F: FC partials (16 rows x 64 cols) -> pbuf ----
        waitflags(cfl, 48, (unsigned)(t + 2), tid);  // all g2done: h2(t) ready
        ushort8* fst = sbuf + 1024;                  // 24 KB region [16:40KB)
        const int n0f = rowbase + (local >> 3) * 16, cg2 = local & 7, ctg = cg2 * 4 + w;
        const int h2rd = 768 + ((t + 1) & 1) * 768;
#pragma unroll
        for (int i = 0; i < 6; ++i) {
          int cc = w * 6 + i;
          const u16* gp = P.Acat + (n0f + (l & 15)) * AROW + h2rd + cc * 32 + ((l >> 4) * 8);
          GLLDS_C(gp, &fst[cc * 64]);
        }
        asm volatile("s_waitcnt vmcnt(0)" ::: "memory");
        __syncthreads();
        const u16* bbase = P.W1p + ((long)ctg << 9) + l * 8;
        f32x4 facc = {};
#pragma unroll 6
        for (int kt = 0; kt < 24; ++kt) {
          ushort8 a = fst[kt * 64 + l];
          ushort8 bf8 = *reinterpret_cast<const ushort8*>(bbase + kt * 16384);
          facc = MFMA_B16(a, bf8, facc);
        }
        int col = ctg * 16 + (l & 15);
        float w2v = P.W2[col], b1v = P.b1[col];
        float pr[4];
#pragma unroll
        for (int reg = 0; reg < 4; ++reg) pr[reg] = fmaxf(facc[reg] + b1v, 0.f) * w2v;
#pragma unroll
        for (int mm = 1; mm < 16; mm <<= 1)
#pragma unroll
          for (int reg = 0; reg < 4; ++reg) pr[reg] += __shfl_xor(pr[reg], mm);
        if ((l & 15) == 0)
#pragma unroll
          for (int reg = 0; reg < 4; ++reg) fbuf[w][(l >> 4) * 4 + reg][0] = pr[reg];
        __syncthreads();
        if (tid < 16)
          ATOMIC_ST(P.pbuf + (n0f + tid) * 8 + cg2,
                    fbuf[0][tid][0] + fbuf[1][tid][0] + fbuf[2][tid][0] + fbuf[3][tid][0]);
        setflag(cfl + 64 + local, (unsigned)(t + 2));  // fdone
      }
    }
  } else {
    // ================= g1p + H blocks =================
    const int jb = local - 48;
    const int n0 = rowbase + jb * 4;
    for (int t = -1; t < 128; ++t) {
      float ov = 0.f;
      if (t < 127) {
        // ---- g1p(t): 64 rows; wave w = gate quadrant w, cols [jb*48,(jb+1)*48) ----
        if (t >= 0) waitflags(cfl + 96, 16, (unsigned)(t + 1), tid);   // h1(t) ready
        for (int p = tid; p < 512; p += 256)
          xsb[p >> 3][p & 7] = P.x[((rowbase + (p >> 3)) * LSEQ + t + 1) * 8 + (p & 7)];
        __syncthreads();
        f32x4 acc[3][4] = {};
        if (t >= 0) {
          ushort8 br1[4][3];
          auto issueA1 = [&](int ki) {
            const u16* gp = P.Acat + (rowbase + w * 16 + (l & 15)) * AROW + ki * 32 + ((l >> 4) * 8);
            GLLDS_C(gp, &sbuf[(ki & 7) * 256 + w * 64]);
          };
          auto baddr1 = [&](int ki, int jj) -> const u16* {
            return P.Bp1 + (((long)(ki * 192 + w * 48 + jb * 3 + jj)) << 9) + l * 8;
          };
          auto g1_step = [&](int kt, const ushort8 (&bu)[3]) {
            __builtin_amdgcn_s_barrier();
            __builtin_amdgcn_sched_barrier(0);
            const int sb8 = (kt & 7) * 256;
            ushort8 a_[4];
#pragma unroll
            for (int rt = 0; rt < 4; ++rt) a_[rt] = sbuf[sb8 + rt * 64 + l];
#pragma unroll
            for (int jj = 0; jj < 3; ++jj)
#pragma unroll
              for (int rt = 0; rt < 4; ++rt)
                acc[jj][rt] = MFMA_B16(a_[rt], bu[jj], acc[jj][rt]);
            __builtin_amdgcn_sched_barrier(0);
          };
#pragma unroll
          for (int p = 0; p < 3; ++p) {
            issueA1(p);
            LOADB(br1[p][0], baddr1(p, 0));
            LOADB(br1[p][1], baddr1(p, 1));
            LOADB(br1[p][2], baddr1(p, 2));
          }
          for (int ko = 0; ko < 5; ++ko) {
#pragma unroll
            for (int u = 0; u < 4; ++u) {
              const int kt = ko * 4 + u;
              issueA1(kt + 3);
              LOADB(br1[(u + 3) & 3][0], baddr1(kt + 3, 0));
              LOADB(br1[(u + 3) & 3][1], baddr1(kt + 3, 1));
              LOADB(br1[(u + 3) & 3][2], baddr1(kt + 3, 2));
              VMW(12);
              g1_step(kt, br1[u]);
            }
          }
          issueA1(23);
          LOADB(br1[3][0], baddr1(23, 0));
          LOADB(br1[3][1], baddr1(23, 1));
          LOADB(br1[3][2], baddr1(23, 2));
          VMW(12); g1_step(20, br1[0]);
          VMW(8);  g1_step(21, br1[1]);
          VMW(4);  g1_step(22, br1[2]);
          VMW(0);  g1_step(23, br1[3]);
          __syncthreads();
        }
        // epilogue: v = acc + bs1 + x(t+1) dot Wih1[:,0:8]; LDS transpose -> 16B stores
        float wc[3][8], bsv[3];
#pragma unroll
        for (int jj = 0; jj < 3; ++jj) {
          int j = w * 768 + (jb * 3 + jj) * 16 + (l & 15);
          bsv[jj] = P.bs1[j];
#pragma unroll
          for (int k = 0; k < 8; ++k) wc[jj][k] = P.Wih1t[k * 3072 + j];
        }
        float* eps = (float*)sbuf;                   // [row64][cin48][quad4]
#pragma unroll
        for (int rt = 0; rt < 4; ++rt)
#pragma unroll
          for (int reg = 0; reg < 4; ++reg) {
            int rl = rt * 16 + (l >> 4) * 4 + reg;
            float xv[8];
#pragma unroll
            for (int k = 0; k < 8; ++k) xv[k] = xsb[rl][k];
#pragma unroll
            for (int jj = 0; jj < 3; ++jj) {
              float v = acc[jj][rt][reg] + bsv[jj];
#pragma unroll
              for (int k = 0; k < 8; ++k) v += xv[k] * wc[jj][k];
              eps[rl * 192 + (jj * 16 + (l & 15)) * 4 + w] = v;
            }
          }
        __syncthreads();
#pragma unroll
        for (int k2 = 0; k2 < 12; ++k2) {
          int idx = tid + k2 * 256;                  // 0..3071
          int row = idx / 48, cl = idx - row * 48;
          u32x4 v = *(const u32x4*)(eps + row * 192 + cl * 4);
          st16_sc(P.g1q + (rowbase + row) * 3072 + (jb * 48 + cl) * 4, v);
        }
        setflag(cfl + 48 + jb, (unsigned)(t + 2));   // g1done

        // stage 48KB g1q mirror for own 4 rows (overlaps fdone wait below)
        waitflags(cfl + 48, 16, (unsigned)(t + 2), tid);
#pragma unroll
        for (int i = 0; i < 12; ++i) {
          int f = w * 12 + i;
          const float* gp = P.g1q + n0 * 3072 + f * 256 + l * 4;
          GLLDS_C(gp, (char*)sbuf + f * 1024);
        }
      }

      // ---- H: out(t) (t>=0), cs(t+1)/h1(t+1) act (t<127) ----
      if (t >= 0) {
        waitflags(cfl + 64, 32, (unsigned)(t + 2), tid);   // all fdone
        if (tid < 4) {
          int n = n0 + tid;
          float pb[8];
#pragma unroll
          for (int i = 0; i < 8; ++i) pb[i] = ATOMIC_LD(P.pbuf + n * 8 + i);
          ov = ((pb[0] + pb[1]) + (pb[2] + pb[3])) + ((pb[4] + pb[5]) + (pb[6] + pb[7])) + P.b2[0];
          P.outs[n * LSEQ + t] = ov;
        }
      }
      if (t < 127) {
        if (tid < 4) {
          int n = n0 + tid;
          float cs = P.sb[n] + P.x[(n * LSEQ + t + 1) * 8] - ov;   // exact fp32
          P.sb[n] = cs;
          P.stores[n * LSEQ + t + 1] = cs;
          csh[tid] = cs;
        }
        asm volatile("s_waitcnt vmcnt(0)" ::: "memory");   // g1q mirror complete
        __syncthreads();
        const int r = tid >> 6, l2 = tid & 63;
        const int n = n0 + r;
        const float* ldsrow = (const float*)sbuf + r * 3072;  // [cin768][quad4]
        float cs = csh[r];
        for (int idx = l2; idx < 96; idx += 64) {    // 8 cols per idx
          int m = idx * 8;
          u32 hp[4];
          f32x4 c1v0 = *(const f32x4*)(P.c1 + n * 768 + m);
          f32x4 c1v1 = *(const f32x4*)(P.c1 + n * 768 + m + 4);
          f32x4 nc0, nc1;
#pragma unroll
          for (int k = 0; k < 8; ++k) {
            int mm = m + k;
            f32x4 q = *(const f32x4*)(ldsrow + mm * 4);
            f32x4 wq = *(const f32x4*)(P.w8q + mm * 4);
            float g0 = q[0] + cs * wq[0], g1v = q[1] + cs * wq[1];
            float g2v = q[2] + cs * wq[2], g3v = q[3] + cs * wq[3];
            float co = (k < 4) ? c1v0[k] : c1v1[k - 4];
            float cn = sigf(g1v) * co + sigf(g0) * tanhfast(g2v);
            float h = sigf(g3v) * tanhfast(cn);
            if (k < 4) nc0[k] = cn; else nc1[k - 4] = cn;
            if (k & 1) hp[k >> 1] |= ((u32)f2bf(h)) << 16; else hp[k >> 1] = f2bf(h);
          }
          *(f32x4*)(P.c1 + n * 768 + m) = nc0;
          *(f32x4*)(P.c1 + n * 768 + m + 4) = nc1;
          st16_sc(P.Acat + n * AROW + m, *(u32x4*)hp);
        }
        setflag(cfl + 96 + jb, (unsigned)(t + 2));   // hdone
      }
    }
  }
}

extern "C" void kernel_launch(void* const* d_in, const int* in_sizes, int n_in,
                              void* d_out, int out_size, void* d_ws, size_t ws_size,
                              hipStream_t stream) {
  const float* x    = (const float*)d_in[0];
  const float* Wih1 = (const float*)d_in[1];
  const float* bih1 = (const float*)d_in[2];
  const float* Whh1 = (const float*)d_in[3];
  const float* bhh1 = (const float*)d_in[4];
  const float* Wih2 = (const float*)d_in[5];
  const float* bih2 = (const float*)d_in[6];
  const float* Whh2 = (const float*)d_in[7];
  const float* bhh2 = (const float*)d_in[8];
  const float* W1   = (const float*)d_in[9];
  const float* b1   = (const float*)d_in[10];
  const float* W2   = (const float*)d_in[11];
  const float* b2   = (const float*)d_in[12];

  char* ws = (char*)d_ws;
  u16* Bp2 = (u16*)(ws + OFF_BP2);
  u16* Bp1 = (u16*)(ws + OFF_BP1);
  u16* W1p = (u16*)(ws + OFF_W1P);
  float* Wih1t = (float*)(ws + OFF_WIH1T);
  float* bs1 = (float*)(ws + OFF_BS1);
  float* bs2 = (float*)(ws + OFF_BS2);
  float* w8q = (float*)(ws + OFF_W8Q);
  float* g1q = (float*)(ws + OFF_G1P);
  float* pbuf = (float*)(ws + OFF_PBUF);
  u16* Acat = (u16*)(ws + OFF_ACAT);
  float* c1 = (float*)(ws + OFF_C1);
  float* c2 = (float*)(ws + OFF_C2);
  float* sb = (float*)(ws + OFF_SB);
  unsigned* bar = (unsigned*)(ws + OFF_BAR);
  float* outs = (float*)d_out;
  float* stores = outs + N_B * LSEQ;

  pack_kernel<<<2048, 256, 0, stream>>>(Wih1, bih1, Whh1, bhh1, Wih2, bih2, Whh2, bhh2, W1,
                                        Bp2, Bp1, W1p, Wih1t, bs1, bs2, w8q);
  (void)hipMemsetAsync(ws + OFF_ZERO, 0, ZERO_BYTES, stream);

  Params Pr = {x, Bp2, Bp1, W1p, Wih1t, bs1, bs2, w8q, b1, W2, b2,
               Acat, g1q, c1, c2, sb, pbuf, bar, outs, stores};
  lstm_fused<<<NBLK, 256, 0, stream>>>(Pr);
}